// Round 1
// baseline (6507.115 us; speedup 1.0000x reference)
//
#include <hip/hip_runtime.h>
#include <hip/hip_bf16.h>
#include <math.h>

typedef short short8 __attribute__((ext_vector_type(8)));
typedef short short4v __attribute__((ext_vector_type(4)));
typedef float f32x4 __attribute__((ext_vector_type(4)));

#define DEVI __device__ __forceinline__

DEVI float bf2f(short s){ union{unsigned u; float f;} x; x.u = ((unsigned)(unsigned short)s) << 16; return x.f; }

// Problem constants
// V=32000 H=1024 S=512 B=16 T=128, SOS=1
// ws layout (bytes)
constexpr size_t o_wout   = 0;                          // bf16 [32000*1024] (65,536,000 B)
constexpr size_t o_encbf  = 0;                          // overlay (dead before wout used)
constexpr size_t o_kbf    = 16777216;                   // overlay
constexpr size_t o_wkbf   = 33554432;                   // overlay
constexpr size_t o_wvbf   = 35651584;                   // overlay
constexpr size_t o_wqtbf  = 37748736;                   // overlay
constexpr size_t o_kq     = 65536000;                   // bf16 [8192*1024]
constexpr size_t o_vbf    = o_kq    + 16777216;         // bf16 [8192*1024]
constexpr size_t o_wih2   = o_vbf   + 16777216;         // bf16 [4096*1024]
constexpr size_t o_whh    = o_wih2  + 8388608;          // bf16 [4096*1024]
constexpr size_t o_hall   = o_whh   + 8388608;          // bf16 [2048*1024]
constexpr size_t o_gconst = o_hall  + 4194304;          // f32 [4096]
constexpr size_t o_sb     = o_gconst+ 16384;            // f32 [8192]
constexpr size_t o_hbf    = o_sb    + 32768;            // bf16 [16*1024]
constexpr size_t o_cst    = o_hbf   + 32768;            // f32 [16*1024]
constexpr size_t o_gbuf   = o_cst   + 65536;            // f32 [16*4096]
constexpr size_t o_ctxp   = o_gbuf  + 262144;           // f32 [16*4*1024]
constexpr size_t o_lsum   = o_ctxp  + 262144;           // f32 [16*4]
constexpr size_t o_lse    = o_lsum  + 256;              // f32 [2048]

// ---------------- elementwise converts ----------------
__global__ void k_convert(const float* __restrict__ src, __hip_bfloat16* __restrict__ dst, int n){
  int i = (blockIdx.x*blockDim.x + threadIdx.x)*4;
  int stride = gridDim.x*blockDim.x*4;
  for (; i < n; i += stride){
    float4 v = *(const float4*)(src+i);
    __hip_bfloat16 o[4] = {__float2bfloat16(v.x),__float2bfloat16(v.y),__float2bfloat16(v.z),__float2bfloat16(v.w)};
    *(short4v*)(dst+i) = *(const short4v*)o;
  }
}

// Wq [1024][1024] f32 -> WqT bf16 (dst[h][d] = src[d][h])
__global__ void k_tcvt(const float* __restrict__ src, __hip_bfloat16* __restrict__ dst){
  __shared__ float tile[64][65];
  int i0 = blockIdx.y*64, j0 = blockIdx.x*64;
  int tr = threadIdx.x >> 6, tc = threadIdx.x & 63;
  for (int p=0;p<16;p++){ int r = p*4 + tr; tile[r][tc] = src[(size_t)(i0+r)*1024 + j0+tc]; }
  __syncthreads();
  for (int p=0;p<16;p++){ int r = p*4 + tr; dst[(size_t)(j0+r)*1024 + i0+tc] = __float2bfloat16(tile[tc][r]); }
}

// Wih2[r][c] = W_ih[r][1024+c], r<4096
__global__ void k_extract(const float* __restrict__ src, __hip_bfloat16* __restrict__ dst){
  int i = blockIdx.x*blockDim.x + threadIdx.x;
  int stride = gridDim.x*blockDim.x;
  for (; i < 4096*1024; i += stride){
    int r = i >> 10, c = i & 1023;
    dst[i] = __float2bfloat16(src[((size_t)r << 11) + 1024 + c]);
  }
}

__global__ void k_init(const float* __restrict__ eh, const float* __restrict__ ec,
                       __hip_bfloat16* __restrict__ hbf, float* __restrict__ cst){
  int i = blockIdx.x*blockDim.x + threadIdx.x;
  if (i < 16384){ hbf[i] = __float2bfloat16(eh[i]); cst[i] = ec[i]; }
}

// gate_const[n] = b_ih[n] + b_hh[n] + emb[SOS]·W_ih[n, 0:1024]
__global__ void k_gconst(const float* __restrict__ emb, const float* __restrict__ Wih,
                         const float* __restrict__ bih, const float* __restrict__ bhh,
                         float* __restrict__ gc){
  int w = threadIdx.x >> 6, lane = threadIdx.x & 63;
  int n = blockIdx.x*4 + w;
  const float* er = emb + 1024;  // SOS = 1
  const float* wr = Wih + (size_t)n*2048;
  float acc = 0.f;
  for (int q=0;q<16;q++){ int k = lane*16+q; acc += er[k]*wr[k]; }
  for (int off=32; off; off>>=1) acc += __shfl_xor(acc, off);
  if (lane==0) gc[n] = acc + bih[n] + bhh[n];
}

// sb[r] = (bq · K[r,:]) / 32
__global__ void k_sb(const __hip_bfloat16* __restrict__ Kb, const float* __restrict__ bq,
                     float* __restrict__ sb){
  int w = threadIdx.x >> 6, lane = threadIdx.x & 63;
  int r = blockIdx.x*4 + w;
  const __hip_bfloat16* kr = Kb + (size_t)r*1024;
  float acc = 0.f;
  for (int q=0;q<16;q++){ int k = lane*16+q; acc += __bfloat162float(kr[k])*bq[k]; }
  for (int off=32; off; off>>=1) acc += __shfl_xor(acc, off);
  if (lane==0) sb[r] = acc * 0.03125f;
}

// ---------------- GEMM: C = scale*(A @ B^T) + bias ----------------
// A [M,K] bf16 row-major, B [N,K] bf16 row-major. EPI 0: C bf16 [M,N].
// EPI 1: C f32 at d_out with row permutation r=(t*16+b) -> (b*128+t), ldc=N.
template<int EPI>
__global__ __launch_bounds__(256) void k_gemm(const __hip_bfloat16* __restrict__ A,
    const __hip_bfloat16* __restrict__ Bm, const float* __restrict__ bias,
    void* __restrict__ Cp, int M, int N, int K, float scale){
  __shared__ __hip_bfloat16 sA[128*40];
  __shared__ __hip_bfloat16 sB[128*40];
  int tid = threadIdx.x;
  int lane = tid & 63, w = tid >> 6;
  int wr = w >> 1, wc = w & 1;
  int m0 = blockIdx.y*128, n0 = blockIdx.x*128;
  int lrow = lane & 15, lk = lane >> 4;
  f32x4 acc[4][4] = {};
  for (int k0 = 0; k0 < K; k0 += 32){
    __syncthreads();
    #pragma unroll
    for (int l0 = 0; l0 < 1024; l0 += 256){
      int l = l0 + tid;
      int half = l >> 9;
      int ch = l & 511;
      int row = ch >> 2, seg = ch & 3;
      const __hip_bfloat16* src = half ? (Bm + (size_t)(n0+row)*K + k0 + seg*8)
                                       : (A  + (size_t)(m0+row)*K + k0 + seg*8);
      __hip_bfloat16* dst = (half ? sB : sA) + row*40 + seg*8;
      *(short8*)dst = *(const short8*)src;
    }
    __syncthreads();
    short8 af[4], bfq[4];
    #pragma unroll
    for (int mi=0;mi<4;mi++) af[mi]  = *(short8*)(sA + (wr*64+mi*16+lrow)*40 + lk*8);
    #pragma unroll
    for (int ni=0;ni<4;ni++) bfq[ni] = *(short8*)(sB + (wc*64+ni*16+lrow)*40 + lk*8);
    #pragma unroll
    for (int mi=0;mi<4;mi++)
      #pragma unroll
      for (int ni=0;ni<4;ni++)
        acc[mi][ni] = __builtin_amdgcn_mfma_f32_16x16x32_bf16(af[mi], bfq[ni], acc[mi][ni], 0,0,0);
  }
  int crow0 = (lane>>4)*4;
  int ccol = lane & 15;
  #pragma unroll
  for (int mi=0;mi<4;mi++)
    #pragma unroll
    for (int ni=0;ni<4;ni++){
      int gn = n0 + wc*64 + ni*16 + ccol;
      float bv = bias ? bias[gn] : 0.0f;
      #pragma unroll
      for (int j=0;j<4;j++){
        int gm = m0 + wr*64 + mi*16 + crow0 + j;
        float v = acc[mi][ni][j]*scale + bv;
        if (EPI==0){
          ((__hip_bfloat16*)Cp)[(size_t)gm*N + gn] = __float2bfloat16(v);
        } else {
          int tt = gm >> 4, bb = gm & 15;
          ((float*)Cp)[(size_t)(bb*128+tt)*N + gn] = v;
        }
      }
    }
}

// ---------------- per-step kernel A: attention partials + h@Whh^T ----------------
__global__ __launch_bounds__(256) void k_stepA(const __hip_bfloat16* __restrict__ hbf,
    const __hip_bfloat16* __restrict__ KQ, const __hip_bfloat16* __restrict__ Vb,
    const float* __restrict__ sb, const __hip_bfloat16* __restrict__ Whh,
    float* __restrict__ ctxp, float* __restrict__ lsum, float* __restrict__ gbuf){
  int tid = threadIdx.x;
  __shared__ __hip_bfloat16 sH[1024];
  __shared__ float sSc[128];
  __shared__ float sE[128];
  __shared__ __hip_bfloat16 sA[16*1032];
  if (blockIdx.x < 64){
    int b = blockIdx.x >> 2, c = blockIdx.x & 3;
    int s0 = c*128;
    *(short4v*)(sH + tid*4) = *(const short4v*)(hbf + b*1024 + tid*4);
    __syncthreads();
    // hoist this thread's h-slice (k = koff + q*64 + e) into registers
    int koff = (tid & 7)*8;
    short8 hreg[16];
    #pragma unroll
    for (int q=0;q<16;q++) hreg[q] = *(short8*)(sH + koff + q*64);
    const float* sbp = sb + b*512 + s0;
    #pragma unroll
    for (int p=0;p<4;p++){
      int row = p*32 + (tid >> 3);
      const __hip_bfloat16* kqp = KQ + (size_t)(b*512 + s0 + row)*1024 + koff;
      float acc = 0.f;
      #pragma unroll
      for (int q=0;q<16;q++){
        short8 kv = *(const short8*)(kqp + q*64);
        short8 hv = hreg[q];
        #pragma unroll
        for (int e=0;e<8;e++) acc += bf2f(hv[e]) * bf2f(kv[e]);
      }
      acc += __shfl_xor(acc, 1); acc += __shfl_xor(acc, 2); acc += __shfl_xor(acc, 4);
      if ((tid & 7) == 0) sSc[row] = acc + sbp[row];
    }
    __syncthreads();
    if (tid < 128) sE[tid] = expf(sSc[tid]);
    __syncthreads();
    if (tid < 64){
      float l2 = sE[tid] + sE[tid+64];
      for (int off=32; off; off>>=1) l2 += __shfl_xor(l2, off);
      if (tid==0) lsum[b*4+c] = l2;
    }
    // ctx partial (unnormalized)
    int h4 = tid*4;
    float a0=0,a1=0,a2=0,a3=0;
    const __hip_bfloat16* vp = Vb + (size_t)(b*512 + s0)*1024 + h4;
    for (int s=0;s<128;s++){
      float ev = sE[s];
      short4v v4 = *(const short4v*)(vp + (size_t)s*1024);
      a0 += ev*bf2f(v4[0]); a1 += ev*bf2f(v4[1]); a2 += ev*bf2f(v4[2]); a3 += ev*bf2f(v4[3]);
    }
    float4 o; o.x=a0; o.y=a1; o.z=a2; o.w=a3;
    *(float4*)(ctxp + (size_t)(b*4+c)*1024 + h4) = o;
  } else {
    int nc = blockIdx.x - 64;
    for (int l = tid; l < 2048; l += 256){
      int bb = l >> 7, off = (l & 127)*8;
      *(short8*)(sA + bb*1032 + off) = *(const short8*)(hbf + bb*1024 + off);
    }
    __syncthreads();
    int w = tid >> 6, lane = tid & 63;
    int lrow = lane & 15, lk = lane >> 4;
    int nw = nc*64 + w*16;
    f32x4 acc = {};
    const __hip_bfloat16* bp = Whh + (size_t)(nw + lrow)*1024 + lk*8;
    for (int k0=0;k0<1024;k0+=32){
      short8 bfr = *(const short8*)(bp + k0);
      short8 afr = *(const short8*)(sA + lrow*1032 + lk*8 + k0);
      acc = __builtin_amdgcn_mfma_f32_16x16x32_bf16(afr, bfr, acc, 0,0,0);
    }
    int ccol = lane & 15, crow0 = (lane>>4)*4;
    #pragma unroll
    for (int j=0;j<4;j++){
      int bb = crow0 + j;
      gbuf[bb*4096 + nw + ccol] = acc[j];
    }
  }
}

// ---------------- per-step kernel B: ctx combine + ctx@Wih2^T + LSTM ----------------
__global__ __launch_bounds__(256) void k_stepB(const float* __restrict__ ctxp,
    const float* __restrict__ lsum, const __hip_bfloat16* __restrict__ Wih2,
    const float* __restrict__ gconst, const float* __restrict__ gbuf,
    float* __restrict__ cst, __hip_bfloat16* __restrict__ hbf,
    __hip_bfloat16* __restrict__ hall, int t,
    float* __restrict__ outH, float* __restrict__ outC){
  __shared__ __hip_bfloat16 sA[16*1032];
  __shared__ float sG[4*256];
  __shared__ float sLinv[16];
  int tid = threadIdx.x;
  int j0 = blockIdx.x*16;
  for (int p=0;p<64;p++){
    int idx = p*256 + tid;
    int bb = idx >> 10, hh = idx & 1023;
    const float* cp = ctxp + (size_t)bb*4096 + hh;
    float s = cp[0] + cp[1024] + cp[2048] + cp[3072];
    sA[bb*1032 + hh] = __float2bfloat16(s);
  }
  if (tid < 16) sLinv[tid] = 1.0f/(lsum[tid*4]+lsum[tid*4+1]+lsum[tid*4+2]+lsum[tid*4+3]);
  __syncthreads();
  int w = tid >> 6, lane = tid & 63;
  int lrow = lane & 15, lk = lane >> 4;
  int n = w*1024 + j0 + lrow;
  f32x4 acc = {};
  const __hip_bfloat16* bp = Wih2 + (size_t)n*1024 + lk*8;
  for (int k0=0;k0<1024;k0+=32){
    short8 bfr = *(const short8*)(bp + k0);
    short8 afr = *(const short8*)(sA + lrow*1032 + lk*8 + k0);
    acc = __builtin_amdgcn_mfma_f32_16x16x32_bf16(afr, bfr, acc, 0,0,0);
  }
  int ccol = lane & 15, crow0 = (lane>>4)*4;
  float gcv = gconst[w*1024 + j0 + ccol];
  #pragma unroll
  for (int j=0;j<4;j++){
    int bb = crow0 + j;
    float gv = gcv + gbuf[bb*4096 + w*1024 + j0 + ccol] + acc[j]*sLinv[bb];
    sG[w*256 + bb*16 + ccol] = gv;
  }
  __syncthreads();
  {
    int bb = tid >> 4, jj = tid & 15;
    int j = j0 + jj;
    float gi = sG[0*256 + bb*16 + jj];
    float gf = sG[1*256 + bb*16 + jj];
    float gg = sG[2*256 + bb*16 + jj];
    float go = sG[3*256 + bb*16 + jj];
    float cold = cst[bb*1024 + j];
    float si = 1.f/(1.f+expf(-gi));
    float sf = 1.f/(1.f+expf(-gf));
    float so = 1.f/(1.f+expf(-go));
    float c2 = sf*cold + si*tanhf(gg);
    float h2 = so*tanhf(c2);
    cst[bb*1024+j] = c2;
    __hip_bfloat16 hb = __float2bfloat16(h2);
    hbf[bb*1024+j] = hb;
    hall[((size_t)t*16+bb)*1024 + j] = hb;
    if (t == 127){ outH[bb*1024+j] = h2; outC[bb*1024+j] = c2; }
  }
}

// ---------------- log-softmax ----------------
__global__ __launch_bounds__(256) void k_lse(const float* __restrict__ out, float* __restrict__ lse){
  __shared__ float red[8];
  int row = blockIdx.x;
  const float* p = out + (size_t)row*32000;
  int tid = threadIdx.x;
  float m = -1e30f;
  for (int i = tid; i < 32000; i += 256) m = fmaxf(m, p[i]);
  for (int off=32; off; off>>=1) m = fmaxf(m, __shfl_xor(m, off));
  if ((tid&63)==0) red[tid>>6] = m;
  __syncthreads();
  m = fmaxf(fmaxf(red[0],red[1]), fmaxf(red[2],red[3]));
  float l = 0.f;
  for (int i = tid; i < 32000; i += 256) l += expf(p[i]-m);
  for (int off=32; off; off>>=1) l += __shfl_xor(l, off);
  if ((tid&63)==0) red[4+(tid>>6)] = l;
  __syncthreads();
  if (tid==0) lse[row] = m + logf(red[4]+red[5]+red[6]+red[7]);
}

__global__ void k_apply(float* __restrict__ out, const float* __restrict__ lse){
  size_t i = (size_t)blockIdx.x*blockDim.x + threadIdx.x;
  size_t stride = (size_t)gridDim.x*blockDim.x;
  for (; i < 16384000u; i += stride){
    float4 v = *(float4*)(out + i*4);
    float L = lse[i / 8000];
    v.x -= L; v.y -= L; v.z -= L; v.w -= L;
    *(float4*)(out + i*4) = v;
  }
}

extern "C" void kernel_launch(void* const* d_in, const int* in_sizes, int n_in,
                              void* d_out, int out_size, void* d_ws, size_t ws_size,
                              hipStream_t stream){
  const float* enc = (const float*)d_in[0];
  const float* eh  = (const float*)d_in[1];
  const float* ec  = (const float*)d_in[2];
  const float* emb = (const float*)d_in[3];
  const float* Wq  = (const float*)d_in[4];
  const float* bq  = (const float*)d_in[5];
  const float* Wk  = (const float*)d_in[6];
  const float* bk  = (const float*)d_in[7];
  const float* Wv  = (const float*)d_in[8];
  const float* bv  = (const float*)d_in[9];
  const float* Wih = (const float*)d_in[10];
  const float* bih = (const float*)d_in[11];
  const float* Whh = (const float*)d_in[12];
  const float* bhh = (const float*)d_in[13];
  const float* Wo  = (const float*)d_in[14];
  const float* bo  = (const float*)d_in[15];

  char* ws = (char*)d_ws;
  __hip_bfloat16* encbf = (__hip_bfloat16*)(ws + o_encbf);
  __hip_bfloat16* kbf   = (__hip_bfloat16*)(ws + o_kbf);
  __hip_bfloat16* wkbf  = (__hip_bfloat16*)(ws + o_wkbf);
  __hip_bfloat16* wvbf  = (__hip_bfloat16*)(ws + o_wvbf);
  __hip_bfloat16* wqtbf = (__hip_bfloat16*)(ws + o_wqtbf);
  __hip_bfloat16* woutbf= (__hip_bfloat16*)(ws + o_wout);
  __hip_bfloat16* kq    = (__hip_bfloat16*)(ws + o_kq);
  __hip_bfloat16* vbf   = (__hip_bfloat16*)(ws + o_vbf);
  __hip_bfloat16* wih2  = (__hip_bfloat16*)(ws + o_wih2);
  __hip_bfloat16* whhbf = (__hip_bfloat16*)(ws + o_whh);
  __hip_bfloat16* hall  = (__hip_bfloat16*)(ws + o_hall);
  float* gconst = (float*)(ws + o_gconst);
  float* sbp    = (float*)(ws + o_sb);
  __hip_bfloat16* hbf = (__hip_bfloat16*)(ws + o_hbf);
  float* cst    = (float*)(ws + o_cst);
  float* gbuf   = (float*)(ws + o_gbuf);
  float* ctxp   = (float*)(ws + o_ctxp);
  float* lsum   = (float*)(ws + o_lsum);
  float* lsep   = (float*)(ws + o_lse);
  float* outP   = (float*)d_out;
  float* outH   = outP + 65536000;
  float* outC   = outH + 16384;

  // ---- precompute ----
  k_convert<<<1024,256,0,stream>>>(enc, encbf, 8388608);
  k_convert<<<256,256,0,stream>>>(Wk, wkbf, 1048576);
  k_convert<<<256,256,0,stream>>>(Wv, wvbf, 1048576);
  k_tcvt<<<dim3(16,16),256,0,stream>>>(Wq, wqtbf);
  k_gemm<0><<<dim3(8,64),256,0,stream>>>(encbf, wkbf, bk, kbf, 8192,1024,1024, 1.f);
  k_gemm<0><<<dim3(8,64),256,0,stream>>>(encbf, wvbf, bv, vbf, 8192,1024,1024, 1.f);
  k_gemm<0><<<dim3(8,64),256,0,stream>>>(kbf, wqtbf, (const float*)nullptr, kq, 8192,1024,1024, 0.03125f);
  k_sb<<<2048,256,0,stream>>>(kbf, bq, sbp);
  k_extract<<<1024,256,0,stream>>>(Wih, wih2);
  k_convert<<<1024,256,0,stream>>>(Whh, whhbf, 4194304);
  k_gconst<<<1024,256,0,stream>>>(emb, Wih, bih, bhh, gconst);
  k_init<<<64,256,0,stream>>>(eh, ec, hbf, cst);

  // ---- recurrence ----
  for (int t = 0; t < 128; ++t){
    k_stepA<<<128,256,0,stream>>>(hbf, kq, vbf, sbp, whhbf, ctxp, lsum, gbuf);
    k_stepB<<<64,256,0,stream>>>(ctxp, lsum, wih2, gconst, gbuf, cst, hbf, hall, t, outH, outC);
  }

  // ---- logits + log-softmax ----
  k_convert<<<2048,256,0,stream>>>(Wo, woutbf, 32768000);
  k_gemm<1><<<dim3(250,16),256,0,stream>>>(hall, woutbf, bo, d_out, 2048,32000,1024, 1.f);
  k_lse<<<2048,256,0,stream>>>(outP, lsep);
  k_apply<<<4096,256,0,stream>>>(outP, lsep);
}